// Round 9
// baseline (370.744 us; speedup 1.0000x reference)
//
#include <hip/hip_runtime.h>

// Problem constants
constexpr int Bb = 4;     // batch
constexpr int Dd = 256;   // channels
constexpr int Nn = 2048;  // query positions
constexpr int Mm = 2048;  // source positions
constexpr int Hh = 4;     // heads
constexpr int D2 = 512;   // 2*D
constexpr int NT = Bb * Nn;  // 8192 total positions

#define FMAXV 3.402823466e38f

typedef _Float16 half8 __attribute__((ext_vector_type(8)));
typedef _Float16 half4v __attribute__((ext_vector_type(4)));
typedef float f32x4 __attribute__((ext_vector_type(4)));

// ---------------------------------------------------------------------------
// Weight prepack (unchanged from R8)
// ---------------------------------------------------------------------------
__global__ __launch_bounds__(256)
void prep_weights_kernel(const float* __restrict__ Wq, const float* __restrict__ bq,
                         const float* __restrict__ Wk, const float* __restrict__ bk,
                         const float* __restrict__ Wv, const float* __restrict__ bv,
                         const float* __restrict__ Wm,
                         const float* __restrict__ W1, const float* __restrict__ b1,
                         const float* __restrict__ gamma, const float* __restrict__ beta,
                         const float* __restrict__ rmean, const float* __restrict__ rvar,
                         const float* __restrict__ W2,
                         _Float16* __restrict__ Wqp, float* __restrict__ bqp,
                         _Float16* __restrict__ Wkvp, float* __restrict__ bkvp,
                         _Float16* __restrict__ Wmp,
                         _Float16* __restrict__ W1p, float* __restrict__ b1f,
                         _Float16* __restrict__ W2p) {
    const int r = blockIdx.x, t = threadIdx.x;
    if (r < 256) {
        const int h = r >> 6, d = r & 63, so = d * Hh + h;
        Wqp[r * 256 + t] = (_Float16)Wq[so * 256 + t];
        if (t == 0) bqp[r] = bq[so];
    } else if (r < 768) {
        const int rr = r - 256, part = rr >> 8, o = rr & 255;
        const int h = o >> 6, d = o & 63, so = d * Hh + h;
        const float* Ws = part ? Wv : Wk;
        const float* bs = part ? bv : bk;
        Wkvp[rr * 256 + t] = (_Float16)Ws[so * 256 + t];
        if (t == 0) bkvp[rr] = bs[so];
    } else if (r < 1024) {
        const int o = r - 768;
        const int h = t >> 6, d = t & 63, sk = d * Hh + h;
        Wmp[o * 256 + t] = (_Float16)Wm[o * 256 + sk];
    } else if (r < 1536) {
        const int o = r - 1024;
        const float s = gamma[o] * rsqrtf(rvar[o] + 1e-3f);
        W1p[o * 512 + t]       = (_Float16)(W1[o * 512 + t] * s);
        W1p[o * 512 + t + 256] = (_Float16)(W1[o * 512 + t + 256] * s);
        if (t == 0) b1f[o] = (b1[o] - rmean[o]) * s + beta[o];
    } else {
        const int o = r - 1536;
        W2p[o * 512 + t]       = (_Float16)W2[o * 512 + t];
        W2p[o * 512 + t + 256] = (_Float16)W2[o * 512 + t + 256];
    }
}

// ---------------------------------------------------------------------------
// Activation prepack (unchanged from R8)
// ---------------------------------------------------------------------------
__global__ __launch_bounds__(256)
void prep_x_kernel(const float* __restrict__ x, const float* __restrict__ source,
                   _Float16* __restrict__ Yp, _Float16* __restrict__ Sp) {
    __shared__ _Float16 Ts[64][72];
    const int z = blockIdx.z, b = z >> 1, which = z & 1;
    const float* src = which ? source : x;
    _Float16* dst = which ? Sp : Yp;
    const int stride = which ? 256 : 512;
    const int c0 = blockIdx.y * 64, n0 = blockIdx.x * 64;
    const int t = threadIdx.x;
    const int cl = t >> 2, np = (t & 3) * 16;
    const float* sp = src + ((size_t)b * Dd + c0 + cl) * Nn + n0 + np;
    #pragma unroll
    for (int i = 0; i < 4; ++i) {
        float4 v = *(const float4*)(sp + i * 4);
        Ts[np + i * 4 + 0][cl] = (_Float16)v.x;
        Ts[np + i * 4 + 1][cl] = (_Float16)v.y;
        Ts[np + i * 4 + 2][cl] = (_Float16)v.z;
        Ts[np + i * 4 + 3][cl] = (_Float16)v.w;
    }
    __syncthreads();
    const int nl = t >> 2, cp = (t & 3) * 16;
    half8 a0 = *(const half8*)&Ts[nl][cp];
    half8 a1 = *(const half8*)&Ts[nl][cp + 8];
    _Float16* dp = dst + ((size_t)b * Nn + n0 + nl) * stride + c0 + cp;
    *(half8*)dp = a0;
    *(half8*)(dp + 8) = a1;
}

// ---------------------------------------------------------------------------
// Mask -> bitmask (R3 kernel, proven innocent by R6 bisection).
// Word w covers mask[w*64 .. w*64+63]; bit i = mask[w*64+i]>0.
// ---------------------------------------------------------------------------
__global__ __launch_bounds__(256)
void mask_bits_kernel(const float* __restrict__ mask,
                      unsigned long long* __restrict__ bits, int nwords) {
    const int lane = threadIdx.x & 63;
    const int wid = (blockIdx.x * blockDim.x + threadIdx.x) >> 6;
    const int stride = (gridDim.x * blockDim.x) >> 6;
    for (int w = wid; w < nwords; w += stride) {
        float v = mask[(size_t)w * 64 + lane];
        unsigned long long b = __ballot(v > 0.f);
        if (lane == 0) bits[w] = b;
    }
}

// ---------------------------------------------------------------------------
// fp16 MFMA GEMM, now 64-thread (1-wave) blocks: one 64n x 64o tile per block.
// Grid (NT/64, O/64). 4x the block count of R8 -> fills all 256 CUs.
// ---------------------------------------------------------------------------
__global__ __launch_bounds__(64)
void gemm16_kernel(const _Float16* __restrict__ A, const _Float16* __restrict__ W,
                   const float* __restrict__ bias,
                   _Float16* __restrict__ dst0, _Float16* __restrict__ dst1,
                   float* __restrict__ dstF,
                   int K, int sA, int sOut, int modeSel, int relu) {
    __shared__ _Float16 Es[16][72];
    const int lane = threadIdx.x & 63, quad = lane >> 4, l16 = lane & 15;
    const int n0 = blockIdx.x * 64;
    const int og0 = blockIdx.y * 64;

    f32x4 acc[4][4] = {};
    #pragma unroll 1
    for (int k0 = 0; k0 < K; k0 += 32) {
        half8 a[4], b[4];
        #pragma unroll
        for (int i = 0; i < 4; ++i)
            a[i] = *(const half8*)(A + (size_t)(n0 + i * 16 + l16) * sA + k0 + quad * 8);
        #pragma unroll
        for (int j = 0; j < 4; ++j)
            b[j] = *(const half8*)(W + (size_t)(og0 + j * 16 + l16) * K + k0 + quad * 8);
        #pragma unroll
        for (int i = 0; i < 4; ++i)
            #pragma unroll
            for (int j = 0; j < 4; ++j)
                acc[i][j] = __builtin_amdgcn_mfma_f32_16x16x32_f16(a[i], b[j], acc[i][j], 0, 0, 0);
    }

    float bcol[4];
    #pragma unroll
    for (int j = 0; j < 4; ++j) bcol[j] = bias[og0 + j * 16 + l16];

    int mode = 0, oloc0 = og0;
    if (modeSel == 2) mode = 2;
    else if (modeSel == 1 && og0 >= 256) { mode = 1; oloc0 = og0 - 256; }

    if (mode == 0) {
        #pragma unroll
        for (int i = 0; i < 4; ++i) {
            #pragma unroll
            for (int j = 0; j < 4; ++j)
                #pragma unroll
                for (int reg = 0; reg < 4; ++reg) {
                    float v = acc[i][j][reg] + bcol[j];
                    if (relu) v = fmaxf(v, 0.f);
                    Es[quad * 4 + reg][j * 16 + l16] = (_Float16)v;
                }
            __asm__ volatile("s_waitcnt lgkmcnt(0)" ::: "memory");
            const int row = lane & 15, oseg = (lane >> 4) * 16;
            half8 e0 = *(const half8*)&Es[row][oseg];
            half8 e1 = *(const half8*)&Es[row][oseg + 8];
            _Float16* dp = dst0 + (size_t)(n0 + i * 16 + row) * sOut + oloc0 + oseg;
            *(half8*)dp = e0;
            *(half8*)(dp + 8) = e1;
            __asm__ volatile("s_waitcnt lgkmcnt(0)" ::: "memory");
        }
    } else if (mode == 1) {
        #pragma unroll
        for (int i = 0; i < 4; ++i) {
            const int ng = n0 + i * 16 + quad * 4;
            const int bidx = ng >> 11, m0 = ng & 2047;
            #pragma unroll
            for (int j = 0; j < 4; ++j) {
                const int o = oloc0 + j * 16 + l16;
                half4v pv;
                #pragma unroll
                for (int reg = 0; reg < 4; ++reg) pv[reg] = (_Float16)(acc[i][j][reg] + bcol[j]);
                *(half4v*)(dst1 + ((size_t)bidx * 256 + o) * (size_t)Mm + m0) = pv;
            }
        }
    } else {
        #pragma unroll
        for (int i = 0; i < 4; ++i) {
            const int ng = n0 + i * 16 + quad * 4;
            const int bidx = ng >> 11, m0 = ng & 2047;
            #pragma unroll
            for (int j = 0; j < 4; ++j) {
                const int o = og0 + j * 16 + l16;
                f32x4 v;
                #pragma unroll
                for (int reg = 0; reg < 4; ++reg) v[reg] = acc[i][j][reg] + bcol[j];
                *(f32x4*)(dstF + ((size_t)bidx * 256 + o) * (size_t)Nn + m0) = v;
            }
        }
    }
}

// ---------------------------------------------------------------------------
// MFMA attention: R7/R8-proven max-aware softmax + m-split, now with the
// bitmask (R6 proved the bit path innocent). 4 u64 mask loads/iter instead of
// 16 scalar float loads -> mask HBM traffic 64 MB -> 2 MB.
// Grid (N/16, H, B) = 2048 blocks, 256 thr.
// ---------------------------------------------------------------------------
__global__ __launch_bounds__(256)
void attn_mfma_kernel(const _Float16* __restrict__ Qp, const _Float16* __restrict__ Kp,
                      const _Float16* __restrict__ Vt,
                      const unsigned long long* __restrict__ Mbits,
                      _Float16* __restrict__ msgp) {
    __shared__ __align__(16) _Float16 Ps[4][16][72];
    __shared__ __align__(16) float Osw[4][16][68];
    __shared__ float Lw[4][16];
    __shared__ float Mw[4][16];

    const int b = blockIdx.z, h = blockIdx.y, n0 = blockIdx.x * 16;
    const int t = threadIdx.x;
    const int w = t >> 6, lane = t & 63, quad = lane >> 4, l16 = lane & 15;

    const _Float16* qp = Qp + ((size_t)b * Nn + n0 + l16) * 256 + h * 64 + quad * 8;
    const half8 qa0 = *(const half8*)(qp);
    const half8 qa1 = *(const half8*)(qp + 32);

    const _Float16* Kbase = Kp + (size_t)b * Nn * 256 + h * 64;
    const _Float16* Vbase = Vt + ((size_t)b * 256 + h * 64 + l16) * (size_t)Mm;
    const unsigned long long* mb = Mbits + ((size_t)b * Nn + n0 + quad * 4) * (Mm / 64);

    float mo[4] = {-FMAXV, -FMAXV, -FMAXV, -FMAXV};
    float lo[4] = {0.f, 0.f, 0.f, 0.f};
    f32x4 O[4] = {};

    const int mbeg = w * (Mm / 4);
    #pragma unroll 1
    for (int it = 0; it < (Mm / 4) / 64; ++it) {
        const int m0 = mbeg + it * 64;
        f32x4 S[4];
        #pragma unroll
        for (int mt = 0; mt < 4; ++mt) {
            const _Float16* kp = Kbase + (size_t)(m0 + mt * 16 + l16) * 256 + quad * 8;
            half8 k0 = *(const half8*)(kp);
            half8 k1 = *(const half8*)(kp + 32);
            f32x4 z = {0.f, 0.f, 0.f, 0.f};
            z = __builtin_amdgcn_mfma_f32_16x16x32_f16(qa0, k0, z, 0, 0, 0);
            z = __builtin_amdgcn_mfma_f32_16x16x32_f16(qa1, k1, z, 0, 0, 0);
            S[mt] = z;
        }
        // ---- mask bits: one u64 per row (element m = m0 + mt*16 + l16,
        //      bit = mt*16+l16 since m0 is 64-aligned) ----
        const int ch = m0 >> 6;
        unsigned int wlo[4], whi[4];
        #pragma unroll
        for (int reg = 0; reg < 4; ++reg) {
            unsigned long long mw = mb[(size_t)reg * (Mm / 64) + ch];
            wlo[reg] = (unsigned int)mw;
            whi[reg] = (unsigned int)(mw >> 32);
        }
        #pragma unroll
        for (int mt = 0; mt < 4; ++mt) {
            const int sh = (mt & 1) * 16 + l16;
            #pragma unroll
            for (int reg = 0; reg < 4; ++reg) {
                const unsigned int bw = (mt & 2) ? whi[reg] : wlo[reg];
                S[mt][reg] = ((bw >> sh) & 1u) ? S[mt][reg] * 0.125f : -FMAXV;
            }
        }
        // ---- online max (R7-proven) ----
        float mn[4], al[4];
        #pragma unroll
        for (int reg = 0; reg < 4; ++reg) {
            float mloc = fmaxf(fmaxf(S[0][reg], S[1][reg]), fmaxf(S[2][reg], S[3][reg]));
            #pragma unroll
            for (int off = 1; off < 16; off <<= 1)
                mloc = fmaxf(mloc, __shfl_xor(mloc, off));
            mn[reg] = fmaxf(mo[reg], mloc);
            al[reg] = __expf(mo[reg] - mn[reg]);
            mo[reg] = mn[reg];
        }
        float p[4][4];
        #pragma unroll
        for (int mt = 0; mt < 4; ++mt)
            #pragma unroll
            for (int reg = 0; reg < 4; ++reg)
                p[mt][reg] = __expf(S[mt][reg] - mn[reg]);
        #pragma unroll
        for (int reg = 0; reg < 4; ++reg)
            lo[reg] = lo[reg] * al[reg] + (p[0][reg] + p[1][reg]) + (p[2][reg] + p[3][reg]);
        #pragma unroll
        for (int mt = 0; mt < 4; ++mt)
            #pragma unroll
            for (int reg = 0; reg < 4; ++reg)
                Ps[w][quad * 4 + reg][mt * 16 + l16] = (_Float16)p[mt][reg];
        __asm__ volatile("s_waitcnt lgkmcnt(0)" ::: "memory");
        half8 pa0 = *(const half8*)&Ps[w][l16][quad * 8];
        half8 pa1 = *(const half8*)&Ps[w][l16][32 + quad * 8];
        #pragma unroll
        for (int dt = 0; dt < 4; ++dt)
            #pragma unroll
            for (int reg = 0; reg < 4; ++reg)
                O[dt][reg] *= al[reg];
        #pragma unroll
        for (int dt = 0; dt < 4; ++dt) {
            const _Float16* vp = Vbase + (size_t)(dt * 16) * Mm + m0 + quad * 8;
            half8 v0 = *(const half8*)(vp);
            half8 v1 = *(const half8*)(vp + 32);
            O[dt] = __builtin_amdgcn_mfma_f32_16x16x32_f16(pa0, v0, O[dt], 0, 0, 0);
            O[dt] = __builtin_amdgcn_mfma_f32_16x16x32_f16(pa1, v1, O[dt], 0, 0, 0);
        }
    }

    #pragma unroll
    for (int reg = 0; reg < 4; ++reg) {
        #pragma unroll
        for (int off = 1; off < 16; off <<= 1)
            lo[reg] += __shfl_xor(lo[reg], off);
    }

    #pragma unroll
    for (int dt = 0; dt < 4; ++dt)
        #pragma unroll
        for (int reg = 0; reg < 4; ++reg)
            Osw[w][quad * 4 + reg][dt * 16 + l16] = O[dt][reg];
    if (l16 == 0) {
        #pragma unroll
        for (int reg = 0; reg < 4; ++reg) {
            Lw[w][quad * 4 + reg] = lo[reg];
            Mw[w][quad * 4 + reg] = mo[reg];
        }
    }
    __syncthreads();

    // max-aware combine; write msgp[b][n][h*64+d] fp16
    const int nrow = t >> 4, dseg = (t & 15) * 4;
    const float m0w = Mw[0][nrow], m1w = Mw[1][nrow], m2w = Mw[2][nrow], m3w = Mw[3][nrow];
    const float ms = fmaxf(fmaxf(m0w, m1w), fmaxf(m2w, m3w));
    const float f0 = __expf(m0w - ms), f1 = __expf(m1w - ms);
    const float f2 = __expf(m2w - ms), f3 = __expf(m3w - ms);
    const float L = f0 * Lw[0][nrow] + f1 * Lw[1][nrow] + f2 * Lw[2][nrow] + f3 * Lw[3][nrow];
    const float inv = 1.0f / L;
    half4v outv;
    #pragma unroll
    for (int dd = 0; dd < 4; ++dd) {
        const int d = dseg + dd;
        float s = f0 * Osw[0][nrow][d] + f1 * Osw[1][nrow][d]
                + f2 * Osw[2][nrow][d] + f3 * Osw[3][nrow][d];
        outv[dd] = (_Float16)(s * inv);
    }
    *(half4v*)(msgp + ((size_t)b * Nn + n0 + nrow) * 256 + h * 64 + dseg) = outv;
}

// ---------------------------------------------------------------------------
extern "C" void kernel_launch(void* const* d_in, const int* in_sizes, int n_in,
                              void* d_out, int out_size, void* d_ws, size_t ws_size,
                              hipStream_t stream) {
    const float* x      = (const float*)d_in[0];
    const float* source = (const float*)d_in[1];
    const float* mask   = (const float*)d_in[2];
    const float* Wq = (const float*)d_in[3];
    const float* bq = (const float*)d_in[4];
    const float* Wk = (const float*)d_in[5];
    const float* bk = (const float*)d_in[6];
    const float* Wv = (const float*)d_in[7];
    const float* bv = (const float*)d_in[8];
    const float* Wm = (const float*)d_in[9];
    const float* bm = (const float*)d_in[10];
    const float* W1 = (const float*)d_in[11];
    const float* b1 = (const float*)d_in[12];
    const float* gamma = (const float*)d_in[13];
    const float* beta  = (const float*)d_in[14];
    const float* rmean = (const float*)d_in[15];
    const float* rvar  = (const float*)d_in[16];
    const float* W2 = (const float*)d_in[17];
    const float* b2 = (const float*)d_in[18];
    float* outp = (float*)d_out;

    // workspace layout (bytes); peak end ~42 MB (< R7-proven 47 MB)
    char* wsb = (char*)d_ws;
    _Float16* Yp   = (_Float16*)wsb;                       // [8192][512]  8 MB
    _Float16* Sp   = (_Float16*)(wsb + (8u << 20));        // [8192][256]  4 MB
    _Float16* Qp   = (_Float16*)(wsb + (12u << 20));       // [8192][256]  4 MB
    _Float16* Kp   = (_Float16*)(wsb + (16u << 20));       // [8192][256]  4 MB
    _Float16* Vt   = (_Float16*)(wsb + (20u << 20));       // [1024][2048] 4 MB
    _Float16* msgp = (_Float16*)(wsb + (24u << 20));       // [8192][256]  4 MB
    _Float16* Hp   = (_Float16*)(wsb + (28u << 20));       // [8192][512]  8 MB
    char* wp = wsb + (36u << 20);
    _Float16* Wqp  = (_Float16*)wp;            wp += 256 * 256 * 2;
    _Float16* Wkvp = (_Float16*)wp;            wp += 512 * 256 * 2;
    _Float16* Wmp  = (_Float16*)wp;            wp += 256 * 256 * 2;
    _Float16* W1p  = (_Float16*)wp;            wp += 512 * 512 * 2;
    _Float16* W2p  = (_Float16*)wp;            wp += 256 * 512 * 2;
    float* bqp  = (float*)wp;                  wp += 256 * 4;
    float* bkvp = (float*)wp;                  wp += 512 * 4;
    float* b1f  = (float*)wp;                  wp += 512 * 4;
    unsigned long long* Mbits = (unsigned long long*)(wsb + (40u << 20));  // 2 MB

    prep_weights_kernel<<<1792, 256, 0, stream>>>(
        Wq, bq, Wk, bk, Wv, bv, Wm, W1, b1, gamma, beta, rmean, rvar, W2,
        Wqp, bqp, Wkvp, bkvp, Wmp, W1p, b1f, W2p);

    const int nwords = Bb * Nn * (Mm / 64);
    mask_bits_kernel<<<512, 256, 0, stream>>>(mask, Mbits, nwords);

    dim3 gPrep(Nn / 64, Dd / 64, Bb * 2);
    prep_x_kernel<<<gPrep, 256, 0, stream>>>(x, source, Yp, Sp);

    // q projection: A=Yp (x cols 0..256, stride 512), out Qp [n][256]
    gemm16_kernel<<<dim3(NT / 64, 4), 64, 0, stream>>>(
        Yp, Wqp, bqp, Qp, nullptr, nullptr, 256, 512, 256, 0, 0);
    // k+v projections: A=Sp, out Kp (mode0) / Vt (mode1)
    gemm16_kernel<<<dim3(NT / 64, 8), 64, 0, stream>>>(
        Sp, Wkvp, bkvp, Kp, Vt, nullptr, 256, 256, 256, 1, 0);

    dim3 gAttn(Nn / 16, Hh, Bb);
    attn_mfma_kernel<<<gAttn, 256, 0, stream>>>(Qp, Kp, Vt, Mbits, msgp);

    // message projection: A=msgp, out -> Yp cols 256..512
    gemm16_kernel<<<dim3(NT / 64, 4), 64, 0, stream>>>(
        msgp, Wmp, bm, Yp + 256, nullptr, nullptr, 256, 256, 512, 0, 0);
    // MLP layer 1 (BN-folded, relu): A=Yp [n][512], out Hp [n][512]
    gemm16_kernel<<<dim3(NT / 64, 8), 64, 0, stream>>>(
        Yp, W1p, b1f, Hp, nullptr, nullptr, 512, 512, 512, 0, 1);
    // MLP layer 2: A=Hp, fp32 out [b][256][n]
    gemm16_kernel<<<dim3(NT / 64, 4), 64, 0, stream>>>(
        Hp, W2p, b2, nullptr, nullptr, outp, 512, 512, 0, 2, 0);
}

// Round 10
// 329.338 us; speedup vs baseline: 1.1257x; 1.1257x over previous
//
#include <hip/hip_runtime.h>

// Problem constants
constexpr int Bb = 4;     // batch
constexpr int Dd = 256;   // channels
constexpr int Nn = 2048;  // query positions
constexpr int Mm = 2048;  // source positions
constexpr int Hh = 4;     // heads
constexpr int D2 = 512;   // 2*D
constexpr int NT = Bb * Nn;  // 8192 total positions

#define FMAXV 3.402823466e38f

typedef _Float16 half8 __attribute__((ext_vector_type(8)));
typedef _Float16 half4v __attribute__((ext_vector_type(4)));
typedef float f32x4 __attribute__((ext_vector_type(4)));

// ---------------------------------------------------------------------------
// Weight prepack (unchanged from R8/R9)
// ---------------------------------------------------------------------------
__global__ __launch_bounds__(256)
void prep_weights_kernel(const float* __restrict__ Wq, const float* __restrict__ bq,
                         const float* __restrict__ Wk, const float* __restrict__ bk,
                         const float* __restrict__ Wv, const float* __restrict__ bv,
                         const float* __restrict__ Wm,
                         const float* __restrict__ W1, const float* __restrict__ b1,
                         const float* __restrict__ gamma, const float* __restrict__ beta,
                         const float* __restrict__ rmean, const float* __restrict__ rvar,
                         const float* __restrict__ W2,
                         _Float16* __restrict__ Wqp, float* __restrict__ bqp,
                         _Float16* __restrict__ Wkvp, float* __restrict__ bkvp,
                         _Float16* __restrict__ Wmp,
                         _Float16* __restrict__ W1p, float* __restrict__ b1f,
                         _Float16* __restrict__ W2p) {
    const int r = blockIdx.x, t = threadIdx.x;
    if (r < 256) {
        const int h = r >> 6, d = r & 63, so = d * Hh + h;
        Wqp[r * 256 + t] = (_Float16)Wq[so * 256 + t];
        if (t == 0) bqp[r] = bq[so];
    } else if (r < 768) {
        const int rr = r - 256, part = rr >> 8, o = rr & 255;
        const int h = o >> 6, d = o & 63, so = d * Hh + h;
        const float* Ws = part ? Wv : Wk;
        const float* bs = part ? bv : bk;
        Wkvp[rr * 256 + t] = (_Float16)Ws[so * 256 + t];
        if (t == 0) bkvp[rr] = bs[so];
    } else if (r < 1024) {
        const int o = r - 768;
        const int h = t >> 6, d = t & 63, sk = d * Hh + h;
        Wmp[o * 256 + t] = (_Float16)Wm[o * 256 + sk];
    } else if (r < 1536) {
        const int o = r - 1024;
        const float s = gamma[o] * rsqrtf(rvar[o] + 1e-3f);
        W1p[o * 512 + t]       = (_Float16)(W1[o * 512 + t] * s);
        W1p[o * 512 + t + 256] = (_Float16)(W1[o * 512 + t + 256] * s);
        if (t == 0) b1f[o] = (b1[o] - rmean[o]) * s + beta[o];
    } else {
        const int o = r - 1536;
        W2p[o * 512 + t]       = (_Float16)W2[o * 512 + t];
        W2p[o * 512 + t + 256] = (_Float16)W2[o * 512 + t + 256];
    }
}

// ---------------------------------------------------------------------------
// Activation prepack (unchanged from R8/R9)
// ---------------------------------------------------------------------------
__global__ __launch_bounds__(256)
void prep_x_kernel(const float* __restrict__ x, const float* __restrict__ source,
                   _Float16* __restrict__ Yp, _Float16* __restrict__ Sp) {
    __shared__ _Float16 Ts[64][72];
    const int z = blockIdx.z, b = z >> 1, which = z & 1;
    const float* src = which ? source : x;
    _Float16* dst = which ? Sp : Yp;
    const int stride = which ? 256 : 512;
    const int c0 = blockIdx.y * 64, n0 = blockIdx.x * 64;
    const int t = threadIdx.x;
    const int cl = t >> 2, np = (t & 3) * 16;
    const float* sp = src + ((size_t)b * Dd + c0 + cl) * Nn + n0 + np;
    #pragma unroll
    for (int i = 0; i < 4; ++i) {
        float4 v = *(const float4*)(sp + i * 4);
        Ts[np + i * 4 + 0][cl] = (_Float16)v.x;
        Ts[np + i * 4 + 1][cl] = (_Float16)v.y;
        Ts[np + i * 4 + 2][cl] = (_Float16)v.z;
        Ts[np + i * 4 + 3][cl] = (_Float16)v.w;
    }
    __syncthreads();
    const int nl = t >> 2, cp = (t & 3) * 16;
    half8 a0 = *(const half8*)&Ts[nl][cp];
    half8 a1 = *(const half8*)&Ts[nl][cp + 8];
    _Float16* dp = dst + ((size_t)b * Nn + n0 + nl) * stride + c0 + cp;
    *(half8*)dp = a0;
    *(half8*)(dp + 8) = a1;
}

// ---------------------------------------------------------------------------
// fp16 MFMA GEMM, 1-wave blocks, explicit two-stage K-pipeline (ping-pong
// register prefetch: load k0+32 while MFMA'ing k0). K multiple of 64.
// ---------------------------------------------------------------------------
__global__ __launch_bounds__(64)
void gemm16_kernel(const _Float16* __restrict__ A, const _Float16* __restrict__ W,
                   const float* __restrict__ bias,
                   _Float16* __restrict__ dst0, _Float16* __restrict__ dst1,
                   float* __restrict__ dstF,
                   int K, int sA, int sOut, int modeSel, int relu) {
    __shared__ _Float16 Es[16][72];
    const int lane = threadIdx.x & 63, quad = lane >> 4, l16 = lane & 15;
    const int n0 = blockIdx.x * 64;
    const int og0 = blockIdx.y * 64;

    const _Float16* aRow[4];
    const _Float16* bRow[4];
    #pragma unroll
    for (int i = 0; i < 4; ++i)
        aRow[i] = A + (size_t)(n0 + i * 16 + l16) * sA + quad * 8;
    #pragma unroll
    for (int j = 0; j < 4; ++j)
        bRow[j] = W + (size_t)(og0 + j * 16 + l16) * K + quad * 8;

    f32x4 acc[4][4] = {};
    half8 a0[4], b0[4], a1[4], b1[4];
    #pragma unroll
    for (int i = 0; i < 4; ++i) a0[i] = *(const half8*)(aRow[i]);
    #pragma unroll
    for (int j = 0; j < 4; ++j) b0[j] = *(const half8*)(bRow[j]);

    #pragma unroll 1
    for (int k0 = 0; k0 < K; k0 += 64) {
        // prefetch stage 1 (k0+32)
        #pragma unroll
        for (int i = 0; i < 4; ++i) a1[i] = *(const half8*)(aRow[i] + k0 + 32);
        #pragma unroll
        for (int j = 0; j < 4; ++j) b1[j] = *(const half8*)(bRow[j] + k0 + 32);
        // compute stage 0
        #pragma unroll
        for (int i = 0; i < 4; ++i)
            #pragma unroll
            for (int j = 0; j < 4; ++j)
                acc[i][j] = __builtin_amdgcn_mfma_f32_16x16x32_f16(a0[i], b0[j], acc[i][j], 0, 0, 0);
        // prefetch next stage 0 (k0+64)
        if (k0 + 64 < K) {
            #pragma unroll
            for (int i = 0; i < 4; ++i) a0[i] = *(const half8*)(aRow[i] + k0 + 64);
            #pragma unroll
            for (int j = 0; j < 4; ++j) b0[j] = *(const half8*)(bRow[j] + k0 + 64);
        }
        // compute stage 1
        #pragma unroll
        for (int i = 0; i < 4; ++i)
            #pragma unroll
            for (int j = 0; j < 4; ++j)
                acc[i][j] = __builtin_amdgcn_mfma_f32_16x16x32_f16(a1[i], b1[j], acc[i][j], 0, 0, 0);
    }

    float bcol[4];
    #pragma unroll
    for (int j = 0; j < 4; ++j) bcol[j] = bias[og0 + j * 16 + l16];

    int mode = 0, oloc0 = og0;
    if (modeSel == 2) mode = 2;
    else if (modeSel == 1 && og0 >= 256) { mode = 1; oloc0 = og0 - 256; }

    if (mode == 0) {
        #pragma unroll
        for (int i = 0; i < 4; ++i) {
            #pragma unroll
            for (int j = 0; j < 4; ++j)
                #pragma unroll
                for (int reg = 0; reg < 4; ++reg) {
                    float v = acc[i][j][reg] + bcol[j];
                    if (relu) v = fmaxf(v, 0.f);
                    Es[quad * 4 + reg][j * 16 + l16] = (_Float16)v;
                }
            __asm__ volatile("s_waitcnt lgkmcnt(0)" ::: "memory");
            const int row = lane & 15, oseg = (lane >> 4) * 16;
            half8 e0 = *(const half8*)&Es[row][oseg];
            half8 e1 = *(const half8*)&Es[row][oseg + 8];
            _Float16* dp = dst0 + (size_t)(n0 + i * 16 + row) * sOut + oloc0 + oseg;
            *(half8*)dp = e0;
            *(half8*)(dp + 8) = e1;
            __asm__ volatile("s_waitcnt lgkmcnt(0)" ::: "memory");
        }
    } else if (mode == 1) {
        #pragma unroll
        for (int i = 0; i < 4; ++i) {
            const int ng = n0 + i * 16 + quad * 4;
            const int bidx = ng >> 11, m0 = ng & 2047;
            #pragma unroll
            for (int j = 0; j < 4; ++j) {
                const int o = oloc0 + j * 16 + l16;
                half4v pv;
                #pragma unroll
                for (int reg = 0; reg < 4; ++reg) pv[reg] = (_Float16)(acc[i][j][reg] + bcol[j]);
                *(half4v*)(dst1 + ((size_t)bidx * 256 + o) * (size_t)Mm + m0) = pv;
            }
        }
    } else {
        #pragma unroll
        for (int i = 0; i < 4; ++i) {
            const int ng = n0 + i * 16 + quad * 4;
            const int bidx = ng >> 11, m0 = ng & 2047;
            #pragma unroll
            for (int j = 0; j < 4; ++j) {
                const int o = og0 + j * 16 + l16;
                f32x4 v;
                #pragma unroll
                for (int reg = 0; reg < 4; ++reg) v[reg] = acc[i][j][reg] + bcol[j];
                *(f32x4*)(dstF + ((size_t)bidx * 256 + o) * (size_t)Nn + m0) = v;
            }
        }
    }
}

// ---------------------------------------------------------------------------
// MFMA attention: R7/R8-proven max-aware softmax + m-split, float mask loads
// (R9 showed mask HBM wasn't the bottleneck; bitmask dropped). Osw stored in
// fp16 -> LDS 27.1 KB -> 18.4 KB -> 8 blocks/CU occupancy ceiling (was 3.3).
// Grid (N/16, H, B) = 2048 blocks, 256 thr.
// ---------------------------------------------------------------------------
__global__ __launch_bounds__(256)
void attn_mfma_kernel(const _Float16* __restrict__ Qp, const _Float16* __restrict__ Kp,
                      const _Float16* __restrict__ Vt, const float* __restrict__ mask,
                      _Float16* __restrict__ msgp) {
    __shared__ __align__(16) _Float16 Ps[4][16][72];   // 9216 B
    __shared__ __align__(16) _Float16 Osw[4][16][68];  // 8704 B (fp16 partials)
    __shared__ float Lw[4][16];
    __shared__ float Mw[4][16];

    const int b = blockIdx.z, h = blockIdx.y, n0 = blockIdx.x * 16;
    const int t = threadIdx.x;
    const int w = t >> 6, lane = t & 63, quad = lane >> 4, l16 = lane & 15;

    const _Float16* qp = Qp + ((size_t)b * Nn + n0 + l16) * 256 + h * 64 + quad * 8;
    const half8 qa0 = *(const half8*)(qp);
    const half8 qa1 = *(const half8*)(qp + 32);

    const _Float16* Kbase = Kp + (size_t)b * Nn * 256 + h * 64;
    const _Float16* Vbase = Vt + ((size_t)b * 256 + h * 64 + l16) * (size_t)Mm;
    const float* mrow = mask + ((size_t)b * Nn + n0 + quad * 4) * Mm + l16;

    float mo[4] = {-FMAXV, -FMAXV, -FMAXV, -FMAXV};
    float lo[4] = {0.f, 0.f, 0.f, 0.f};
    f32x4 O[4] = {};

    const int mbeg = w * (Mm / 4);
    #pragma unroll 1
    for (int it = 0; it < (Mm / 4) / 64; ++it) {
        const int m0 = mbeg + it * 64;
        f32x4 S[4];
        #pragma unroll
        for (int mt = 0; mt < 4; ++mt) {
            const _Float16* kp = Kbase + (size_t)(m0 + mt * 16 + l16) * 256 + quad * 8;
            half8 k0 = *(const half8*)(kp);
            half8 k1 = *(const half8*)(kp + 32);
            f32x4 z = {0.f, 0.f, 0.f, 0.f};
            z = __builtin_amdgcn_mfma_f32_16x16x32_f16(qa0, k0, z, 0, 0, 0);
            z = __builtin_amdgcn_mfma_f32_16x16x32_f16(qa1, k1, z, 0, 0, 0);
            S[mt] = z;
        }
        float mk[4][4];
        #pragma unroll
        for (int mt = 0; mt < 4; ++mt)
            #pragma unroll
            for (int reg = 0; reg < 4; ++reg)
                mk[mt][reg] = mrow[(size_t)reg * Mm + m0 + mt * 16];
        #pragma unroll
        for (int mt = 0; mt < 4; ++mt)
            #pragma unroll
            for (int reg = 0; reg < 4; ++reg)
                S[mt][reg] = (mk[mt][reg] > 0.f) ? S[mt][reg] * 0.125f : -FMAXV;
        float mn[4], al[4];
        #pragma unroll
        for (int reg = 0; reg < 4; ++reg) {
            float mloc = fmaxf(fmaxf(S[0][reg], S[1][reg]), fmaxf(S[2][reg], S[3][reg]));
            #pragma unroll
            for (int off = 1; off < 16; off <<= 1)
                mloc = fmaxf(mloc, __shfl_xor(mloc, off));
            mn[reg] = fmaxf(mo[reg], mloc);
            al[reg] = __expf(mo[reg] - mn[reg]);
            mo[reg] = mn[reg];
        }
        float p[4][4];
        #pragma unroll
        for (int mt = 0; mt < 4; ++mt)
            #pragma unroll
            for (int reg = 0; reg < 4; ++reg)
                p[mt][reg] = __expf(S[mt][reg] - mn[reg]);
        #pragma unroll
        for (int reg = 0; reg < 4; ++reg)
            lo[reg] = lo[reg] * al[reg] + (p[0][reg] + p[1][reg]) + (p[2][reg] + p[3][reg]);
        #pragma unroll
        for (int mt = 0; mt < 4; ++mt)
            #pragma unroll
            for (int reg = 0; reg < 4; ++reg)
                Ps[w][quad * 4 + reg][mt * 16 + l16] = (_Float16)p[mt][reg];
        __asm__ volatile("s_waitcnt lgkmcnt(0)" ::: "memory");
        half8 pa0 = *(const half8*)&Ps[w][l16][quad * 8];
        half8 pa1 = *(const half8*)&Ps[w][l16][32 + quad * 8];
        #pragma unroll
        for (int dt = 0; dt < 4; ++dt)
            #pragma unroll
            for (int reg = 0; reg < 4; ++reg)
                O[dt][reg] *= al[reg];
        #pragma unroll
        for (int dt = 0; dt < 4; ++dt) {
            const _Float16* vp = Vbase + (size_t)(dt * 16) * Mm + m0 + quad * 8;
            half8 v0 = *(const half8*)(vp);
            half8 v1 = *(const half8*)(vp + 32);
            O[dt] = __builtin_amdgcn_mfma_f32_16x16x32_f16(pa0, v0, O[dt], 0, 0, 0);
            O[dt] = __builtin_amdgcn_mfma_f32_16x16x32_f16(pa1, v1, O[dt], 0, 0, 0);
        }
    }

    #pragma unroll
    for (int reg = 0; reg < 4; ++reg) {
        #pragma unroll
        for (int off = 1; off < 16; off <<= 1)
            lo[reg] += __shfl_xor(lo[reg], off);
    }

    // wave partials -> LDS (O in fp16; scale is O(1..30), rel err 5e-4 -> safe)
    #pragma unroll
    for (int dt = 0; dt < 4; ++dt)
        #pragma unroll
        for (int reg = 0; reg < 4; ++reg)
            Osw[w][quad * 4 + reg][dt * 16 + l16] = (_Float16)O[dt][reg];
    if (l16 == 0) {
        #pragma unroll
        for (int reg = 0; reg < 4; ++reg) {
            Lw[w][quad * 4 + reg] = lo[reg];
            Mw[w][quad * 4 + reg] = mo[reg];
        }
    }
    __syncthreads();

    // max-aware combine; write msgp[b][n][h*64+d] fp16
    const int nrow = t >> 4, dseg = (t & 15) * 4;
    const float m0w = Mw[0][nrow], m1w = Mw[1][nrow], m2w = Mw[2][nrow], m3w = Mw[3][nrow];
    const float ms = fmaxf(fmaxf(m0w, m1w), fmaxf(m2w, m3w));
    const float f0 = __expf(m0w - ms), f1 = __expf(m1w - ms);
    const float f2 = __expf(m2w - ms), f3 = __expf(m3w - ms);
    const float L = f0 * Lw[0][nrow] + f1 * Lw[1][nrow] + f2 * Lw[2][nrow] + f3 * Lw[3][nrow];
    const float inv = 1.0f / L;
    half4v outv;
    #pragma unroll
    for (int dd = 0; dd < 4; ++dd) {
        const int d = dseg + dd;
        float s = f0 * (float)Osw[0][nrow][d] + f1 * (float)Osw[1][nrow][d]
                + f2 * (float)Osw[2][nrow][d] + f3 * (float)Osw[3][nrow][d];
        outv[dd] = (_Float16)(s * inv);
    }
    *(half4v*)(msgp + ((size_t)b * Nn + n0 + nrow) * 256 + h * 64 + dseg) = outv;
}

// ---------------------------------------------------------------------------
extern "C" void kernel_launch(void* const* d_in, const int* in_sizes, int n_in,
                              void* d_out, int out_size, void* d_ws, size_t ws_size,
                              hipStream_t stream) {
    const float* x      = (const float*)d_in[0];
    const float* source = (const float*)d_in[1];
    const float* mask   = (const float*)d_in[2];
    const float* Wq = (const float*)d_in[3];
    const float* bq = (const float*)d_in[4];
    const float* Wk = (const float*)d_in[5];
    const float* bk = (const float*)d_in[6];
    const float* Wv = (const float*)d_in[7];
    const float* bv = (const float*)d_in[8];
    const float* Wm = (const float*)d_in[9];
    const float* bm = (const float*)d_in[10];
    const float* W1 = (const float*)d_in[11];
    const float* b1 = (const float*)d_in[12];
    const float* gamma = (const float*)d_in[13];
    const float* beta  = (const float*)d_in[14];
    const float* rmean = (const float*)d_in[15];
    const float* rvar  = (const float*)d_in[16];
    const float* W2 = (const float*)d_in[17];
    const float* b2 = (const float*)d_in[18];
    float* outp = (float*)d_out;

    // workspace layout (bytes)
    char* wsb = (char*)d_ws;
    _Float16* Yp   = (_Float16*)wsb;                       // [8192][512]  8 MB
    _Float16* Sp   = (_Float16*)(wsb + (8u << 20));        // [8192][256]  4 MB
    _Float16* Qp   = (_Float16*)(wsb + (12u << 20));       // [8192][256]  4 MB
    _Float16* Kp   = (_Float16*)(wsb + (16u << 20));       // [8192][256]  4 MB
    _Float16* Vt   = (_Float16*)(wsb + (20u << 20));       // [1024][2048] 4 MB
    _Float16* msgp = (_Float16*)(wsb + (24u << 20));       // [8192][256]  4 MB
    _Float16* Hp   = (_Float16*)(wsb + (28u << 20));       // [8192][512]  8 MB
    char* wp = wsb + (36u << 20);
    _Float16* Wqp  = (_Float16*)wp;            wp += 256 * 256 * 2;
    _Float16* Wkvp = (_Float16*)wp;            wp += 512 * 256 * 2;
    _Float16* Wmp  = (_Float16*)wp;            wp += 256 * 256 * 2;
    _Float16* W1p  = (_Float16*)wp;            wp += 512 * 512 * 2;
    _Float16* W2p  = (_Float16*)wp;            wp += 256 * 512 * 2;
    float* bqp  = (float*)wp;                  wp += 256 * 4;
    float* bkvp = (float*)wp;                  wp += 512 * 4;
    float* b1f  = (float*)wp;                  wp += 512 * 4;

    prep_weights_kernel<<<1792, 256, 0, stream>>>(
        Wq, bq, Wk, bk, Wv, bv, Wm, W1, b1, gamma, beta, rmean, rvar, W2,
        Wqp, bqp, Wkvp, bkvp, Wmp, W1p, b1f, W2p);

    dim3 gPrep(Nn / 64, Dd / 64, Bb * 2);
    prep_x_kernel<<<gPrep, 256, 0, stream>>>(x, source, Yp, Sp);

    // q projection: A=Yp (x cols 0..256, stride 512), out Qp [n][256]
    gemm16_kernel<<<dim3(NT / 64, 4), 64, 0, stream>>>(
        Yp, Wqp, bqp, Qp, nullptr, nullptr, 256, 512, 256, 0, 0);
    // k+v projections: A=Sp, out Kp (mode0) / Vt (mode1)
    gemm16_kernel<<<dim3(NT / 64, 8), 64, 0, stream>>>(
        Sp, Wkvp, bkvp, Kp, Vt, nullptr, 256, 256, 256, 1, 0);

    dim3 gAttn(Nn / 16, Hh, Bb);
    attn_mfma_kernel<<<gAttn, 256, 0, stream>>>(Qp, Kp, Vt, mask, msgp);

    // message projection: A=msgp, out -> Yp cols 256..512
    gemm16_kernel<<<dim3(NT / 64, 4), 64, 0, stream>>>(
        msgp, Wmp, bm, Yp + 256, nullptr, nullptr, 256, 256, 512, 0, 0);
    // MLP layer 1 (BN-folded, relu): A=Yp [n][512], out Hp [n][512]
    gemm16_kernel<<<dim3(NT / 64, 8), 64, 0, stream>>>(
        Yp, W1p, b1f, Hp, nullptr, nullptr, 512, 512, 512, 0, 1);
    // MLP layer 2: A=Hp, fp32 out [b][256][n]
    gemm16_kernel<<<dim3(NT / 64, 4), 64, 0, stream>>>(
        Hp, W2p, b2, nullptr, nullptr, outp, 512, 512, 0, 2, 0);
}